// Round 1
// baseline (9380.840 us; speedup 1.0000x reference)
//
#include <hip/hip_runtime.h>
#include <hip/hip_bf16.h>
#include <math.h>

// Fused LM-head cross-entropy: loss = mean_valid( logsumexp(x@W^T) - logit[y] )
// N=4096 tokens, H=4096 hidden, V=128000 vocab.
// Workspace layout (needs 32MB + 32KB):
//   pm[1000][4096]  per-(vtile,row) tile max          (16MB)
//   pl[1000][4096]  per-(vtile,row) tile sumexp       (16MB)
//   tgt[4096]       target logits (fp32 exact)
//   lse[4096]       per-row logsumexp

#define N_ROWS 4096
#define H_DIM  4096
#define V_DIM  128000
#define BM 128
#define BN 128
#define BK 64
#define NT_N (N_ROWS / BM)     // 32
#define NT_V (V_DIM / BN)      // 1000
#define KSTEPS (H_DIM / BK)    // 64
#define IGNORE_INDEX (-100)

typedef __attribute__((ext_vector_type(8))) short bf16x8;
typedef __attribute__((ext_vector_type(4))) float f32x4;

__device__ __forceinline__ unsigned short f2bf(float f) {
    union { float f; unsigned int u; } v; v.f = f;
    return (unsigned short)((v.u + 0x8000u) >> 16);  // round-half-up to bf16
}

__global__ __launch_bounds__(256, 2)
void lmce_gemm_kernel(const float* __restrict__ X, const float* __restrict__ W,
                      float* __restrict__ pm, float* __restrict__ pl)
{
    __shared__ __align__(16) ushort lsA[2][BM * BK];
    __shared__ __align__(16) ushort lsB[2][BN * BK];
    __shared__ float red_m[2][BM];
    __shared__ float red_l[2][BM];

    // bijective XCD swizzle: nwg = 32000, divisible by 8.
    const int nwg = NT_N * NT_V;
    int orig = blockIdx.x;
    int wg = (orig & 7) * (nwg >> 3) + (orig >> 3);
    int vtile = wg / NT_N;
    int ntile = wg - vtile * NT_N;

    int tid  = threadIdx.x;
    int lane = tid & 63;
    int wave = tid >> 6;
    int wr = wave >> 1, wc = wave & 1;   // 2x2 wave grid, each wave 64x64 out
    int fr = lane & 15;                  // fragment row/col
    int kg = lane >> 4;                  // k-group 0..3

    // staging: thread t handles rows i*16 + (t>>4), cols (t&15)*4 .. +3 (fp32)
    int srow = tid >> 4;          // 0..15
    int scol = (tid & 15) * 4;    // 0..60

    const float* pa[8];
    const float* pb[8];
    int swz[8];
    #pragma unroll
    for (int i = 0; i < 8; ++i) {
        int r = i * 16 + srow;
        pa[i] = X + (size_t)(ntile * BM + r) * H_DIM + scol;
        pb[i] = W + (size_t)(vtile * BN + r) * H_DIM + scol;
        swz[i] = (r * (BK * 2) + scol * 2) ^ ((r & 7) << 4);
    }

    // LDS read offsets for MFMA fragments (constant per thread)
    int offA[2][4], offB[2][4];
    #pragma unroll
    for (int kh = 0; kh < 2; ++kh) {
        #pragma unroll
        for (int i = 0; i < 4; ++i) {
            int rowA = wr * 64 + i * 16 + fr;
            offA[kh][i] = (rowA * (BK * 2) + (kg * 8 + kh * 32) * 2) ^ ((rowA & 7) << 4);
            int rowB = wc * 64 + i * 16 + fr;
            offB[kh][i] = (rowB * (BK * 2) + (kg * 8 + kh * 32) * 2) ^ ((rowB & 7) << 4);
        }
    }

    f32x4 aReg[8], bReg[8];
    f32x4 acc[4][4];
    #pragma unroll
    for (int i = 0; i < 4; ++i)
        #pragma unroll
        for (int j = 0; j < 4; ++j)
            acc[i][j] = (f32x4){0.f, 0.f, 0.f, 0.f};

    // prologue: load + stage k-step 0 into buf 0
    #pragma unroll
    for (int i = 0; i < 8; ++i) {
        aReg[i] = *(const f32x4*)(pa[i]);
        bReg[i] = *(const f32x4*)(pb[i]);
    }
    #pragma unroll
    for (int i = 0; i < 8; ++i) {
        ushort4 qa, qb;
        qa.x = f2bf(aReg[i].x); qa.y = f2bf(aReg[i].y); qa.z = f2bf(aReg[i].z); qa.w = f2bf(aReg[i].w);
        qb.x = f2bf(bReg[i].x); qb.y = f2bf(bReg[i].y); qb.z = f2bf(bReg[i].z); qb.w = f2bf(bReg[i].w);
        *(ushort4*)((char*)lsA[0] + swz[i]) = qa;
        *(ushort4*)((char*)lsB[0] + swz[i]) = qb;
    }
    __syncthreads();

    for (int kt = 0; kt < KSTEPS; ++kt) {
        int cur = kt & 1;
        int k0n = (kt + 1) * BK;
        if (kt + 1 < KSTEPS) {   // issue next-tile global loads early (hide under MFMA)
            #pragma unroll
            for (int i = 0; i < 8; ++i) {
                aReg[i] = *(const f32x4*)(pa[i] + k0n);
                bReg[i] = *(const f32x4*)(pb[i] + k0n);
            }
        }
        const char* Ab = (const char*)lsA[cur];
        const char* Bb = (const char*)lsB[cur];
        #pragma unroll
        for (int kh = 0; kh < 2; ++kh) {
            bf16x8 af[4], bff[4];
            #pragma unroll
            for (int i = 0; i < 4; ++i) {
                af[i]  = *(const bf16x8*)(Ab + offA[kh][i]);
                bff[i] = *(const bf16x8*)(Bb + offB[kh][i]);
            }
            #pragma unroll
            for (int mi = 0; mi < 4; ++mi)
                #pragma unroll
                for (int ni = 0; ni < 4; ++ni)
                    acc[mi][ni] = __builtin_amdgcn_mfma_f32_16x16x32_bf16(af[mi], bff[ni], acc[mi][ni], 0, 0, 0);
        }
        if (kt + 1 < KSTEPS) {   // stage next tile into the other buffer
            int nxt = cur ^ 1;
            #pragma unroll
            for (int i = 0; i < 8; ++i) {
                ushort4 qa, qb;
                qa.x = f2bf(aReg[i].x); qa.y = f2bf(aReg[i].y); qa.z = f2bf(aReg[i].z); qa.w = f2bf(aReg[i].w);
                qb.x = f2bf(bReg[i].x); qb.y = f2bf(bReg[i].y); qb.z = f2bf(bReg[i].z); qb.w = f2bf(bReg[i].w);
                *(ushort4*)((char*)lsA[nxt] + swz[i]) = qa;
                *(ushort4*)((char*)lsB[nxt] + swz[i]) = qb;
            }
        }
        __syncthreads();
    }

    // Epilogue: per-row (over this block's 128 cols) max and sumexp.
    // C/D layout (16x16x32): col = lane&15, row = (lane>>4)*4 + reg.
    #pragma unroll
    for (int mi = 0; mi < 4; ++mi) {
        #pragma unroll
        for (int j = 0; j < 4; ++j) {
            float mx = acc[mi][0][j];
            mx = fmaxf(mx, acc[mi][1][j]);
            mx = fmaxf(mx, acc[mi][2][j]);
            mx = fmaxf(mx, acc[mi][3][j]);
            #pragma unroll
            for (int s = 1; s < 16; s <<= 1)
                mx = fmaxf(mx, __shfl_xor(mx, s, 64));
            float se = 0.f;
            #pragma unroll
            for (int ni = 0; ni < 4; ++ni)
                se += __expf(acc[mi][ni][j] - mx);
            #pragma unroll
            for (int s = 1; s < 16; s <<= 1)
                se += __shfl_xor(se, s, 64);
            if (fr == 0) {
                int rloc = wr * 64 + mi * 16 + kg * 4 + j;
                red_m[wc][rloc] = mx;
                red_l[wc][rloc] = se;
            }
        }
    }
    __syncthreads();
    if (tid < BM) {
        float m0 = red_m[0][tid], m1 = red_m[1][tid];
        float l0 = red_l[0][tid], l1 = red_l[1][tid];
        float mm = fmaxf(m0, m1);
        float ll = l0 * __expf(m0 - mm) + l1 * __expf(m1 - mm);
        size_t idx = (size_t)vtile * N_ROWS + (size_t)(ntile * BM + tid);
        pm[idx] = mm;
        pl[idx] = ll;
    }
}

// tgt[row] = dot(x[row], W[y[row]]) in fp32 (exact vs reference)
__global__ void lmce_tgt_kernel(const float* __restrict__ X, const float* __restrict__ W,
                                const int* __restrict__ y, float* __restrict__ tgt)
{
    int row = blockIdx.x;
    int tid = threadIdx.x;
    int yv = y[row];
    float s = 0.f;
    if (yv >= 0 && yv < V_DIM) {
        const float* xr = X + (size_t)row * H_DIM;
        const float* wrow = W + (size_t)yv * H_DIM;
        #pragma unroll
        for (int j = 0; j < 4; ++j) {
            int idx = (tid + j * 256) * 4;
            f32x4 a = *(const f32x4*)(xr + idx);
            f32x4 b = *(const f32x4*)(wrow + idx);
            s += a.x * b.x + a.y * b.y + a.z * b.z + a.w * b.w;
        }
    }
    #pragma unroll
    for (int sh = 1; sh < 64; sh <<= 1) s += __shfl_xor(s, sh, 64);
    __shared__ float sred[4];
    if ((tid & 63) == 0) sred[tid >> 6] = s;
    __syncthreads();
    if (tid == 0) tgt[row] = sred[0] + sred[1] + sred[2] + sred[3];
}

// merge 1000 per-vtile (m,l) partials per row -> lse[row]
// 64 blocks x 256 threads; lane->row for coalesced partial reads.
__global__ void lmce_lse_kernel(const float* __restrict__ pm, const float* __restrict__ pl,
                                float* __restrict__ lse)
{
    int tid = threadIdx.x;
    int row = blockIdx.x * 64 + (tid & 63);
    int part = tid >> 6;   // 0..3, each scans 250 vtiles
    float m = -INFINITY, l = 0.f;
    for (int vt = part * 250; vt < (part + 1) * 250; ++vt) {
        size_t idx = (size_t)vt * N_ROWS + row;
        float m2 = pm[idx], l2 = pl[idx];
        float mm = fmaxf(m, m2);
        l = l * __expf(m - mm) + l2 * __expf(m2 - mm);
        m = mm;
    }
    __shared__ float sm[4][64], sl[4][64];
    sm[part][tid & 63] = m;
    sl[part][tid & 63] = l;
    __syncthreads();
    if (tid < 64) {
        float M = sm[0][tid], L = sl[0][tid];
        #pragma unroll
        for (int p = 1; p < 4; ++p) {
            float m2 = sm[p][tid], l2 = sl[p][tid];
            float mm = fmaxf(M, m2);
            L = L * __expf(M - mm) + l2 * __expf(m2 - mm);
            M = mm;
        }
        lse[blockIdx.x * 64 + tid] = M + logf(L);
    }
}

__global__ void lmce_final_kernel(const float* __restrict__ lse, const float* __restrict__ tgt,
                                  const int* __restrict__ y, float* __restrict__ out)
{
    int tid = threadIdx.x;
    float s = 0.f, c = 0.f;
    for (int i = tid; i < N_ROWS; i += 256) {
        if (y[i] != IGNORE_INDEX) {
            s += lse[i] - tgt[i];
            c += 1.f;
        }
    }
    #pragma unroll
    for (int sh = 1; sh < 64; sh <<= 1) {
        s += __shfl_xor(s, sh, 64);
        c += __shfl_xor(c, sh, 64);
    }
    __shared__ float ss[4], cc[4];
    if ((tid & 63) == 0) { ss[tid >> 6] = s; cc[tid >> 6] = c; }
    __syncthreads();
    if (tid == 0) {
        float S = ss[0] + ss[1] + ss[2] + ss[3];
        float C = cc[0] + cc[1] + cc[2] + cc[3];
        out[0] = S / fmaxf(C, 1.f);
    }
}

extern "C" void kernel_launch(void* const* d_in, const int* in_sizes, int n_in,
                              void* d_out, int out_size, void* d_ws, size_t ws_size,
                              hipStream_t stream)
{
    const float* X = (const float*)d_in[0];   // [4096, 4096] fp32
    const int*   y = (const int*)d_in[1];     // [4096] labels
    const float* W = (const float*)d_in[2];   // [128000, 4096] fp32
    float* out = (float*)d_out;

    char* ws = (char*)d_ws;
    float* pm  = (float*)ws;
    float* pl  = (float*)(ws + (size_t)NT_V * N_ROWS * sizeof(float));
    float* tgt = (float*)(ws + 2 * (size_t)NT_V * N_ROWS * sizeof(float));
    float* lse = tgt + N_ROWS;

    lmce_gemm_kernel<<<NT_N * NT_V, 256, 0, stream>>>(X, W, pm, pl);
    lmce_tgt_kernel<<<N_ROWS, 256, 0, stream>>>(X, W, y, tgt);
    lmce_lse_kernel<<<N_ROWS / 64, 256, 0, stream>>>(pm, pl, lse);
    lmce_final_kernel<<<1, 256, 0, stream>>>(lse, tgt, y, out);
}

// Round 2
// 7522.351 us; speedup vs baseline: 1.2471x; 1.2471x over previous
//
#include <hip/hip_runtime.h>
#include <hip/hip_bf16.h>
#include <math.h>

// Fused LM-head cross-entropy: loss = mean_valid( logsumexp(x@W^T) - logit[y] )
// N=4096 tokens, H=4096 hidden, V=128000 vocab.
//
// Round 2: pre-convert W,X to bf16 in ws (halves GEMM HBM traffic, kills
// inner-loop cvt VALU), GEMM stages via global_load_lds width=16 (m97
// structure). Fallback to round-1 fp32-staging GEMM if ws too small.

#define N_ROWS 4096
#define H_DIM  4096
#define V_DIM  128000
#define BM 128
#define BN 128
#define BK 64
#define NT_N (N_ROWS / BM)     // 32
#define NT_V (V_DIM / BN)      // 1000
#define KSTEPS (H_DIM / BK)    // 64
#define IGNORE_INDEX (-100)

typedef __attribute__((ext_vector_type(8))) short bf16x8;
typedef __attribute__((ext_vector_type(4))) float f32x4;
typedef const __attribute__((address_space(1))) unsigned int* gas1_u32;
typedef __attribute__((address_space(3))) unsigned int* las3_u32;

__device__ __forceinline__ unsigned short f2bf(float f) {
    union { float f; unsigned int u; } v; v.f = f;
    return (unsigned short)((v.u + 0x8000u) >> 16);  // round-half-up to bf16
}

// ---------------- fp32 -> bf16 conversion (memory-bound) ----------------
__global__ void cvt_f32_bf16_kernel(const float* __restrict__ in,
                                    ushort* __restrict__ out, size_t n)
{
    size_t i = ((size_t)blockIdx.x * blockDim.x + threadIdx.x) * 8;
    size_t stride = (size_t)gridDim.x * blockDim.x * 8;
    for (; i < n; i += stride) {
        f32x4 a = *(const f32x4*)(in + i);
        f32x4 b = *(const f32x4*)(in + i + 4);
        ushort4 o0 = { f2bf(a.x), f2bf(a.y), f2bf(a.z), f2bf(a.w) };
        ushort4 o1 = { f2bf(b.x), f2bf(b.y), f2bf(b.z), f2bf(b.w) };
        *(ushort4*)(out + i) = o0;
        *(ushort4*)(out + i + 4) = o1;
    }
}

// ---------------- bf16 GEMM via global_load_lds (m97 structure) ----------------
__global__ __launch_bounds__(256)
void lmce_gemm_bf16_kernel(const ushort* __restrict__ Xb, const ushort* __restrict__ Wb,
                           float* __restrict__ pm, float* __restrict__ pl)
{
    __shared__ __align__(16) ushort lsA[BM * BK];   // 16KB, linear row-major [128][64]
    __shared__ __align__(16) ushort lsB[BN * BK];   // 16KB
    __shared__ float red_m[2][BM];
    __shared__ float red_l[2][BM];

    // bijective XCD swizzle: nwg = 32000 divisible by 8.
    const int nwg = NT_N * NT_V;
    int orig = blockIdx.x;
    int wg = (orig & 7) * (nwg >> 3) + (orig >> 3);
    int vtile = wg / NT_N;
    int ntile = wg - vtile * NT_N;

    int tid  = threadIdx.x;
    int lane = tid & 63;
    int w    = tid >> 6;
    int wr = w >> 1, wc = w & 1;     // 2x2 wave grid, each wave 64x64 out
    int fr = lane & 15;
    int kg = lane >> 4;

    // --- staging setup: wave w, inst i covers tile bytes [w*4096+i*1024, +1024) ---
    // HW writes lane l at lds_base + l*16; global src is per-lane.
    const char* gA[4];
    const char* gB[4];
    las3_u32 ldsA[4], ldsB[4];
    #pragma unroll
    for (int i = 0; i < 4; ++i) {
        int boff = w * 4096 + i * 1024 + lane * 16;
        int row  = boff >> 7;         // 128 B per k-row (64 bf16)
        int colb = boff & 127;
        gA[i] = (const char*)Xb + (size_t)(ntile * BM + row) * (H_DIM * 2) + colb;
        gB[i] = (const char*)Wb + (size_t)(vtile * BN + row) * (H_DIM * 2) + colb;
        int lbase = w * 4096 + i * 1024;   // wave-uniform
        ldsA[i] = (las3_u32)((char*)lsA + lbase);
        ldsB[i] = (las3_u32)((char*)lsB + lbase);
    }

    // --- LDS fragment read offsets (linear layout) ---
    int offA[2][4], offB[2][4];
    #pragma unroll
    for (int kh = 0; kh < 2; ++kh) {
        #pragma unroll
        for (int i = 0; i < 4; ++i) {
            offA[kh][i] = (wr * 64 + i * 16 + fr) * 128 + kg * 16 + kh * 64;
            offB[kh][i] = (wc * 64 + i * 16 + fr) * 128 + kg * 16 + kh * 64;
        }
    }

    f32x4 acc[4][4];
    #pragma unroll
    for (int i = 0; i < 4; ++i)
        #pragma unroll
        for (int j = 0; j < 4; ++j)
            acc[i][j] = (f32x4){0.f, 0.f, 0.f, 0.f};

    for (int kt = 0; kt < KSTEPS; ++kt) {
        size_t ko = (size_t)kt * (BK * 2);
        #pragma unroll
        for (int i = 0; i < 4; ++i) {
            __builtin_amdgcn_global_load_lds((gas1_u32)(gA[i] + ko), ldsA[i], 16, 0, 0);
            __builtin_amdgcn_global_load_lds((gas1_u32)(gB[i] + ko), ldsB[i], 16, 0, 0);
        }
        __syncthreads();   // drains vmcnt(0): LDS tile ready
        #pragma unroll
        for (int kh = 0; kh < 2; ++kh) {
            bf16x8 af[4], bf_[4];
            #pragma unroll
            for (int i = 0; i < 4; ++i) {
                af[i]  = *(const bf16x8*)((const char*)lsA + offA[kh][i]);
                bf_[i] = *(const bf16x8*)((const char*)lsB + offB[kh][i]);
            }
            #pragma unroll
            for (int mi = 0; mi < 4; ++mi)
                #pragma unroll
                for (int ni = 0; ni < 4; ++ni)
                    acc[mi][ni] = __builtin_amdgcn_mfma_f32_16x16x32_bf16(af[mi], bf_[ni], acc[mi][ni], 0, 0, 0);
        }
        __syncthreads();   // all waves done reading before next overwrite
    }

    // Epilogue: per-row (over this block's 128 cols) max and sumexp.
    // C/D layout (16x16x32): col = lane&15, row = (lane>>4)*4 + reg.
    #pragma unroll
    for (int mi = 0; mi < 4; ++mi) {
        #pragma unroll
        for (int j = 0; j < 4; ++j) {
            float mx = acc[mi][0][j];
            mx = fmaxf(mx, acc[mi][1][j]);
            mx = fmaxf(mx, acc[mi][2][j]);
            mx = fmaxf(mx, acc[mi][3][j]);
            #pragma unroll
            for (int s = 1; s < 16; s <<= 1)
                mx = fmaxf(mx, __shfl_xor(mx, s, 64));
            float se = 0.f;
            #pragma unroll
            for (int ni = 0; ni < 4; ++ni)
                se += __expf(acc[mi][ni][j] - mx);
            #pragma unroll
            for (int s = 1; s < 16; s <<= 1)
                se += __shfl_xor(se, s, 64);
            if (fr == 0) {
                int rloc = wr * 64 + mi * 16 + kg * 4 + j;
                red_m[wc][rloc] = mx;
                red_l[wc][rloc] = se;
            }
        }
    }
    __syncthreads();
    if (tid < BM) {
        float m0 = red_m[0][tid], m1 = red_m[1][tid];
        float l0 = red_l[0][tid], l1 = red_l[1][tid];
        float mm = fmaxf(m0, m1);
        float ll = l0 * __expf(m0 - mm) + l1 * __expf(m1 - mm);
        size_t idx = (size_t)vtile * N_ROWS + (size_t)(ntile * BM + tid);
        pm[idx] = mm;
        pl[idx] = ll;
    }
}

// ---------------- round-1 fp32-staging GEMM (fallback if ws too small) ----------------
__global__ __launch_bounds__(256, 2)
void lmce_gemm_f32_kernel(const float* __restrict__ X, const float* __restrict__ W,
                          float* __restrict__ pm, float* __restrict__ pl)
{
    __shared__ __align__(16) ushort lsA[2][BM * BK];
    __shared__ __align__(16) ushort lsB[2][BN * BK];
    __shared__ float red_m[2][BM];
    __shared__ float red_l[2][BM];

    const int nwg = NT_N * NT_V;
    int orig = blockIdx.x;
    int wg = (orig & 7) * (nwg >> 3) + (orig >> 3);
    int vtile = wg / NT_N;
    int ntile = wg - vtile * NT_N;

    int tid  = threadIdx.x;
    int lane = tid & 63;
    int wave = tid >> 6;
    int wr = wave >> 1, wc = wave & 1;
    int fr = lane & 15;
    int kg = lane >> 4;

    int srow = tid >> 4;
    int scol = (tid & 15) * 4;

    const float* pa[8];
    const float* pb[8];
    int swz[8];
    #pragma unroll
    for (int i = 0; i < 8; ++i) {
        int r = i * 16 + srow;
        pa[i] = X + (size_t)(ntile * BM + r) * H_DIM + scol;
        pb[i] = W + (size_t)(vtile * BN + r) * H_DIM + scol;
        swz[i] = (r * (BK * 2) + scol * 2) ^ ((r & 7) << 4);
    }

    int offA[2][4], offB[2][4];
    #pragma unroll
    for (int kh = 0; kh < 2; ++kh) {
        #pragma unroll
        for (int i = 0; i < 4; ++i) {
            int rowA = wr * 64 + i * 16 + fr;
            offA[kh][i] = (rowA * (BK * 2) + (kg * 8 + kh * 32) * 2) ^ ((rowA & 7) << 4);
            int rowB = wc * 64 + i * 16 + fr;
            offB[kh][i] = (rowB * (BK * 2) + (kg * 8 + kh * 32) * 2) ^ ((rowB & 7) << 4);
        }
    }

    f32x4 aReg[8], bReg[8];
    f32x4 acc[4][4];
    #pragma unroll
    for (int i = 0; i < 4; ++i)
        #pragma unroll
        for (int j = 0; j < 4; ++j)
            acc[i][j] = (f32x4){0.f, 0.f, 0.f, 0.f};

    #pragma unroll
    for (int i = 0; i < 8; ++i) {
        aReg[i] = *(const f32x4*)(pa[i]);
        bReg[i] = *(const f32x4*)(pb[i]);
    }
    #pragma unroll
    for (int i = 0; i < 8; ++i) {
        ushort4 qa, qb;
        qa.x = f2bf(aReg[i].x); qa.y = f2bf(aReg[i].y); qa.z = f2bf(aReg[i].z); qa.w = f2bf(aReg[i].w);
        qb.x = f2bf(bReg[i].x); qb.y = f2bf(bReg[i].y); qb.z = f2bf(bReg[i].z); qb.w = f2bf(bReg[i].w);
        *(ushort4*)((char*)lsA[0] + swz[i]) = qa;
        *(ushort4*)((char*)lsB[0] + swz[i]) = qb;
    }
    __syncthreads();

    for (int kt = 0; kt < KSTEPS; ++kt) {
        int cur = kt & 1;
        int k0n = (kt + 1) * BK;
        if (kt + 1 < KSTEPS) {
            #pragma unroll
            for (int i = 0; i < 8; ++i) {
                aReg[i] = *(const f32x4*)(pa[i] + k0n);
                bReg[i] = *(const f32x4*)(pb[i] + k0n);
            }
        }
        const char* Ab = (const char*)lsA[cur];
        const char* Bb = (const char*)lsB[cur];
        #pragma unroll
        for (int kh = 0; kh < 2; ++kh) {
            bf16x8 af[4], bff[4];
            #pragma unroll
            for (int i = 0; i < 4; ++i) {
                af[i]  = *(const bf16x8*)(Ab + offA[kh][i]);
                bff[i] = *(const bf16x8*)(Bb + offB[kh][i]);
            }
            #pragma unroll
            for (int mi = 0; mi < 4; ++mi)
                #pragma unroll
                for (int ni = 0; ni < 4; ++ni)
                    acc[mi][ni] = __builtin_amdgcn_mfma_f32_16x16x32_bf16(af[mi], bff[ni], acc[mi][ni], 0, 0, 0);
        }
        if (kt + 1 < KSTEPS) {
            int nxt = cur ^ 1;
            #pragma unroll
            for (int i = 0; i < 8; ++i) {
                ushort4 qa, qb;
                qa.x = f2bf(aReg[i].x); qa.y = f2bf(aReg[i].y); qa.z = f2bf(aReg[i].z); qa.w = f2bf(aReg[i].w);
                qb.x = f2bf(bReg[i].x); qb.y = f2bf(bReg[i].y); qb.z = f2bf(bReg[i].z); qb.w = f2bf(bReg[i].w);
                *(ushort4*)((char*)lsA[nxt] + swz[i]) = qa;
                *(ushort4*)((char*)lsB[nxt] + swz[i]) = qb;
            }
        }
        __syncthreads();
    }

    #pragma unroll
    for (int mi = 0; mi < 4; ++mi) {
        #pragma unroll
        for (int j = 0; j < 4; ++j) {
            float mx = acc[mi][0][j];
            mx = fmaxf(mx, acc[mi][1][j]);
            mx = fmaxf(mx, acc[mi][2][j]);
            mx = fmaxf(mx, acc[mi][3][j]);
            #pragma unroll
            for (int s = 1; s < 16; s <<= 1)
                mx = fmaxf(mx, __shfl_xor(mx, s, 64));
            float se = 0.f;
            #pragma unroll
            for (int ni = 0; ni < 4; ++ni)
                se += __expf(acc[mi][ni][j] - mx);
            #pragma unroll
            for (int s = 1; s < 16; s <<= 1)
                se += __shfl_xor(se, s, 64);
            if (fr == 0) {
                int rloc = wr * 64 + mi * 16 + kg * 4 + j;
                red_m[wc][rloc] = mx;
                red_l[wc][rloc] = se;
            }
        }
    }
    __syncthreads();
    if (tid < BM) {
        float m0 = red_m[0][tid], m1 = red_m[1][tid];
        float l0 = red_l[0][tid], l1 = red_l[1][tid];
        float mm = fmaxf(m0, m1);
        float ll = l0 * __expf(m0 - mm) + l1 * __expf(m1 - mm);
        size_t idx = (size_t)vtile * N_ROWS + (size_t)(ntile * BM + tid);
        pm[idx] = mm;
        pl[idx] = ll;
    }
}

// tgt[row] = dot(x[row], W[y[row]]) in fp32 (exact vs reference)
__global__ void lmce_tgt_kernel(const float* __restrict__ X, const float* __restrict__ W,
                                const int* __restrict__ y, float* __restrict__ tgt)
{
    int row = blockIdx.x;
    int tid = threadIdx.x;
    int yv = y[row];
    float s = 0.f;
    if (yv >= 0 && yv < V_DIM) {
        const float* xr = X + (size_t)row * H_DIM;
        const float* wrow = W + (size_t)yv * H_DIM;
        #pragma unroll
        for (int j = 0; j < 4; ++j) {
            int idx = (tid + j * 256) * 4;
            f32x4 a = *(const f32x4*)(xr + idx);
            f32x4 b = *(const f32x4*)(wrow + idx);
            s += a.x * b.x + a.y * b.y + a.z * b.z + a.w * b.w;
        }
    }
    #pragma unroll
    for (int sh = 1; sh < 64; sh <<= 1) s += __shfl_xor(s, sh, 64);
    __shared__ float sred[4];
    if ((tid & 63) == 0) sred[tid >> 6] = s;
    __syncthreads();
    if (tid == 0) tgt[row] = sred[0] + sred[1] + sred[2] + sred[3];
}

// merge 1000 per-vtile (m,l) partials per row -> lse[row]
__global__ void lmce_lse_kernel(const float* __restrict__ pm, const float* __restrict__ pl,
                                float* __restrict__ lse)
{
    int tid = threadIdx.x;
    int row = blockIdx.x * 64 + (tid & 63);
    int part = tid >> 6;
    float m = -INFINITY, l = 0.f;
    for (int vt = part * 250; vt < (part + 1) * 250; ++vt) {
        size_t idx = (size_t)vt * N_ROWS + row;
        float m2 = pm[idx], l2 = pl[idx];
        float mm = fmaxf(m, m2);
        l = l * __expf(m - mm) + l2 * __expf(m2 - mm);
        m = mm;
    }
    __shared__ float sm[4][64], sl[4][64];
    sm[part][tid & 63] = m;
    sl[part][tid & 63] = l;
    __syncthreads();
    if (tid < 64) {
        float M = sm[0][tid], L = sl[0][tid];
        #pragma unroll
        for (int p = 1; p < 4; ++p) {
            float m2 = sm[p][tid], l2 = sl[p][tid];
            float mm = fmaxf(M, m2);
            L = L * __expf(M - mm) + l2 * __expf(m2 - mm);
            M = mm;
        }
        lse[blockIdx.x * 64 + tid] = M + logf(L);
    }
}

__global__ void lmce_final_kernel(const float* __restrict__ lse, const float* __restrict__ tgt,
                                  const int* __restrict__ y, float* __restrict__ out)
{
    int tid = threadIdx.x;
    float s = 0.f, c = 0.f;
    for (int i = tid; i < N_ROWS; i += 256) {
        if (y[i] != IGNORE_INDEX) {
            s += lse[i] - tgt[i];
            c += 1.f;
        }
    }
    #pragma unroll
    for (int sh = 1; sh < 64; sh <<= 1) {
        s += __shfl_xor(s, sh, 64);
        c += __shfl_xor(c, sh, 64);
    }
    __shared__ float ss[4], cc[4];
    if ((tid & 63) == 0) { ss[tid >> 6] = s; cc[tid >> 6] = c; }
    __syncthreads();
    if (tid == 0) {
        float S = ss[0] + ss[1] + ss[2] + ss[3];
        float C = cc[0] + cc[1] + cc[2] + cc[3];
        out[0] = S / fmaxf(C, 1.f);
    }
}

extern "C" void kernel_launch(void* const* d_in, const int* in_sizes, int n_in,
                              void* d_out, int out_size, void* d_ws, size_t ws_size,
                              hipStream_t stream)
{
    const float* X = (const float*)d_in[0];   // [4096, 4096] fp32
    const int*   y = (const int*)d_in[1];     // [4096] labels (int32 from harness)
    const float* W = (const float*)d_in[2];   // [128000, 4096] fp32
    float* out = (float*)d_out;

    char* ws = (char*)d_ws;
    // layout: pm(16,384,000) pl(16,384,000) tgt(16,384) lse(16,384) pad Xb(33,554,432) Wb(1,048,576,000)
    const size_t OFF_PL  = 16384000;
    const size_t OFF_TGT = 32768000;
    const size_t OFF_LSE = 32784384;
    const size_t OFF_XB  = 32800768;
    const size_t OFF_WB  = 66355200;
    const size_t REQ     = OFF_WB + (size_t)V_DIM * H_DIM * 2;  // ~1.04 GB

    float* pm  = (float*)ws;
    float* pl  = (float*)(ws + OFF_PL);
    float* tgt = (float*)(ws + OFF_TGT);
    float* lse = (float*)(ws + OFF_LSE);

    if (ws_size >= REQ) {
        ushort* Xb = (ushort*)(ws + OFF_XB);
        ushort* Wb = (ushort*)(ws + OFF_WB);
        cvt_f32_bf16_kernel<<<2048, 256, 0, stream>>>(W, Wb, (size_t)V_DIM * H_DIM);
        cvt_f32_bf16_kernel<<<512, 256, 0, stream>>>(X, Xb, (size_t)N_ROWS * H_DIM);
        lmce_gemm_bf16_kernel<<<NT_N * NT_V, 256, 0, stream>>>(Xb, Wb, pm, pl);
    } else {
        lmce_gemm_f32_kernel<<<NT_N * NT_V, 256, 0, stream>>>(X, W, pm, pl);
    }
    lmce_tgt_kernel<<<N_ROWS, 256, 0, stream>>>(X, W, y, tgt);
    lmce_lse_kernel<<<N_ROWS / 64, 256, 0, stream>>>(pm, pl, lse);
    lmce_final_kernel<<<1, 256, 0, stream>>>(lse, tgt, y, out);
}

// Round 3
// 6891.792 us; speedup vs baseline: 1.3612x; 1.0915x over previous
//
#include <hip/hip_runtime.h>
#include <hip/hip_bf16.h>
#include <math.h>

// Fused LM-head cross-entropy: loss = mean_valid( logsumexp(x@W^T) - logit[y] )
// N=4096 tokens, H=4096 hidden, V=128000 vocab.
//
// Round 3: T2 both-sides XOR swizzle (pre-swizzled global source + swizzled
// ds_read, linear gload_lds dest) + T3-minimum 2-phase prefetch (double-
// buffered LDS, stage next tile before computing current, 1 barrier/K-step).

#define N_ROWS 4096
#define H_DIM  4096
#define V_DIM  128000
#define BM 128
#define BN 128
#define BK 64
#define NT_N (N_ROWS / BM)     // 32
#define NT_V (V_DIM / BN)      // 1000
#define KSTEPS (H_DIM / BK)    // 64
#define IGNORE_INDEX (-100)
#define TILE_BYTES (BM * BK * 2)   // 16384

typedef __attribute__((ext_vector_type(8))) short bf16x8;
typedef __attribute__((ext_vector_type(4))) float f32x4;
typedef const __attribute__((address_space(1))) unsigned int* gas1_u32;
typedef __attribute__((address_space(3))) unsigned int* las3_u32;

__device__ __forceinline__ unsigned short f2bf(float f) {
    union { float f; unsigned int u; } v; v.f = f;
    return (unsigned short)((v.u + 0x8000u) >> 16);  // round-half-up to bf16
}

// ---------------- fp32 -> bf16 conversion (memory-bound) ----------------
__global__ void cvt_f32_bf16_kernel(const float* __restrict__ in,
                                    ushort* __restrict__ out, size_t n)
{
    size_t i = ((size_t)blockIdx.x * blockDim.x + threadIdx.x) * 8;
    size_t stride = (size_t)gridDim.x * blockDim.x * 8;
    for (; i < n; i += stride) {
        f32x4 a = *(const f32x4*)(in + i);
        f32x4 b = *(const f32x4*)(in + i + 4);
        ushort4 o0 = { f2bf(a.x), f2bf(a.y), f2bf(a.z), f2bf(a.w) };
        ushort4 o1 = { f2bf(b.x), f2bf(b.y), f2bf(b.z), f2bf(b.w) };
        *(ushort4*)(out + i) = o0;
        *(ushort4*)(out + i + 4) = o1;
    }
}

// ------- bf16 GEMM: gload_lds + both-sides swizzle + 2-phase prefetch -------
__global__ __launch_bounds__(256)
void lmce_gemm_bf16_kernel(const ushort* __restrict__ Xb, const ushort* __restrict__ Wb,
                           float* __restrict__ pm, float* __restrict__ pl)
{
    __shared__ __align__(16) ushort lsA[2][BM * BK];   // 2 x 16KB
    __shared__ __align__(16) ushort lsB[2][BN * BK];   // 2 x 16KB
    __shared__ float red_m[2][BM];
    __shared__ float red_l[2][BM];

    // bijective XCD swizzle: nwg = 32000 divisible by 8. Each XCD gets a
    // contiguous chunk of wg space = consecutive ntiles of a vtile (shared
    // 1MB W panel stays L2-resident per XCD).
    const int nwg = NT_N * NT_V;
    int orig = blockIdx.x;
    int wg = (orig & 7) * (nwg >> 3) + (orig >> 3);
    int vtile = wg / NT_N;
    int ntile = wg - vtile * NT_N;

    int tid  = threadIdx.x;
    int lane = tid & 63;
    int w    = tid >> 6;
    int wr = w >> 1, wc = w & 1;     // 2x2 wave grid, each wave 64x64 out
    int fr = lane & 15;
    int kg = lane >> 4;

    // --- staging: wave w, inst i covers LDS tile bytes [w*4096+i*1024, +1024),
    // lane l writes 16B at +l*16 (linear dest, HW requirement).
    // Source is pre-swizzled so that LDS holds the st-swizzled layout:
    //   LDS(row, colbyte) = global(row, colbyte ^ ((row&7)<<4))
    const char* gA[4];
    const char* gB[4];
    unsigned ldsOffA[4], ldsOffB[4];
    #pragma unroll
    for (int i = 0; i < 4; ++i) {
        int o    = w * 4096 + i * 1024 + lane * 16;  // within-tile linear byte
        int row  = o >> 7;                           // 128B per k-row (64 bf16)
        int colb = (o & 127) ^ ((row & 7) << 4);     // pre-swizzled source col
        gA[i] = (const char*)Xb + (size_t)(ntile * BM + row) * (H_DIM * 2) + colb;
        gB[i] = (const char*)Wb + (size_t)(vtile * BN + row) * (H_DIM * 2) + colb;
        unsigned lbase = w * 4096 + i * 1024;        // wave-uniform dest base
        ldsOffA[i] = lbase;
        ldsOffB[i] = lbase;
    }

    // --- swizzled LDS fragment read offsets ---
    int offA[2][4], offB[2][4];
    #pragma unroll
    for (int kh = 0; kh < 2; ++kh) {
        #pragma unroll
        for (int i = 0; i < 4; ++i) {
            int rowA = wr * 64 + i * 16 + fr;
            offA[kh][i] = rowA * 128 + ((kg * 16 + kh * 64) ^ ((rowA & 7) << 4));
            int rowB = wc * 64 + i * 16 + fr;
            offB[kh][i] = rowB * 128 + ((kg * 16 + kh * 64) ^ ((rowB & 7) << 4));
        }
    }

    f32x4 acc[4][4];
    #pragma unroll
    for (int i = 0; i < 4; ++i)
        #pragma unroll
        for (int j = 0; j < 4; ++j)
            acc[i][j] = (f32x4){0.f, 0.f, 0.f, 0.f};

    // prologue: stage K-step 0 into buffer 0
    #pragma unroll
    for (int i = 0; i < 4; ++i) {
        __builtin_amdgcn_global_load_lds((gas1_u32)(gA[i]), (las3_u32)((char*)lsA[0] + ldsOffA[i]), 16, 0, 0);
        __builtin_amdgcn_global_load_lds((gas1_u32)(gB[i]), (las3_u32)((char*)lsB[0] + ldsOffB[i]), 16, 0, 0);
    }
    __syncthreads();

    int cur = 0;
    for (int kt = 0; kt < KSTEPS; ++kt) {
        // issue next tile's staging loads BEFORE compute (overlap w/ MFMA)
        if (kt + 1 < KSTEPS) {
            size_t ko = (size_t)(kt + 1) * (BK * 2);
            int nxt = cur ^ 1;
            #pragma unroll
            for (int i = 0; i < 4; ++i) {
                __builtin_amdgcn_global_load_lds((gas1_u32)(gA[i] + ko), (las3_u32)((char*)lsA[nxt] + ldsOffA[i]), 16, 0, 0);
                __builtin_amdgcn_global_load_lds((gas1_u32)(gB[i] + ko), (las3_u32)((char*)lsB[nxt] + ldsOffB[i]), 16, 0, 0);
            }
        }
        const char* Ab = (const char*)lsA[cur];
        const char* Bb = (const char*)lsB[cur];
        #pragma unroll
        for (int kh = 0; kh < 2; ++kh) {
            bf16x8 af[4], bf_[4];
            #pragma unroll
            for (int i = 0; i < 4; ++i) {
                af[i]  = *(const bf16x8*)(Ab + offA[kh][i]);
                bf_[i] = *(const bf16x8*)(Bb + offB[kh][i]);
            }
            #pragma unroll
            for (int mi = 0; mi < 4; ++mi)
                #pragma unroll
                for (int ni = 0; ni < 4; ++ni)
                    acc[mi][ni] = __builtin_amdgcn_mfma_f32_16x16x32_bf16(af[mi], bf_[ni], acc[mi][ni], 0, 0, 0);
        }
        // barrier drains vmcnt(0) (next tile staged) + lgkmcnt (reads done)
        __syncthreads();
        cur ^= 1;
    }

    // Epilogue: per-row (over this block's 128 cols) max and sumexp.
    // C/D layout (16x16x32): col = lane&15, row = (lane>>4)*4 + reg.
    #pragma unroll
    for (int mi = 0; mi < 4; ++mi) {
        #pragma unroll
        for (int j = 0; j < 4; ++j) {
            float mx = acc[mi][0][j];
            mx = fmaxf(mx, acc[mi][1][j]);
            mx = fmaxf(mx, acc[mi][2][j]);
            mx = fmaxf(mx, acc[mi][3][j]);
            #pragma unroll
            for (int s = 1; s < 16; s <<= 1)
                mx = fmaxf(mx, __shfl_xor(mx, s, 64));
            float se = 0.f;
            #pragma unroll
            for (int ni = 0; ni < 4; ++ni)
                se += __expf(acc[mi][ni][j] - mx);
            #pragma unroll
            for (int s = 1; s < 16; s <<= 1)
                se += __shfl_xor(se, s, 64);
            if (fr == 0) {
                int rloc = wr * 64 + mi * 16 + kg * 4 + j;
                red_m[wc][rloc] = mx;
                red_l[wc][rloc] = se;
            }
        }
    }
    __syncthreads();
    if (tid < BM) {
        float m0 = red_m[0][tid], m1 = red_m[1][tid];
        float l0 = red_l[0][tid], l1 = red_l[1][tid];
        float mm = fmaxf(m0, m1);
        float ll = l0 * __expf(m0 - mm) + l1 * __expf(m1 - mm);
        size_t idx = (size_t)vtile * N_ROWS + (size_t)(ntile * BM + tid);
        pm[idx] = mm;
        pl[idx] = ll;
    }
}

// ---------------- round-1 fp32-staging GEMM (fallback if ws too small) ----------------
__global__ __launch_bounds__(256, 2)
void lmce_gemm_f32_kernel(const float* __restrict__ X, const float* __restrict__ W,
                          float* __restrict__ pm, float* __restrict__ pl)
{
    __shared__ __align__(16) ushort lsA[2][BM * BK];
    __shared__ __align__(16) ushort lsB[2][BN * BK];
    __shared__ float red_m[2][BM];
    __shared__ float red_l[2][BM];

    const int nwg = NT_N * NT_V;
    int orig = blockIdx.x;
    int wg = (orig & 7) * (nwg >> 3) + (orig >> 3);
    int vtile = wg / NT_N;
    int ntile = wg - vtile * NT_N;

    int tid  = threadIdx.x;
    int lane = tid & 63;
    int wave = tid >> 6;
    int wr = wave >> 1, wc = wave & 1;
    int fr = lane & 15;
    int kg = lane >> 4;

    int srow = tid >> 4;
    int scol = (tid & 15) * 4;

    const float* pa[8];
    const float* pb[8];
    int swz[8];
    #pragma unroll
    for (int i = 0; i < 8; ++i) {
        int r = i * 16 + srow;
        pa[i] = X + (size_t)(ntile * BM + r) * H_DIM + scol;
        pb[i] = W + (size_t)(vtile * BN + r) * H_DIM + scol;
        swz[i] = (r * (BK * 2) + scol * 2) ^ ((r & 7) << 4);
    }

    int offA[2][4], offB[2][4];
    #pragma unroll
    for (int kh = 0; kh < 2; ++kh) {
        #pragma unroll
        for (int i = 0; i < 4; ++i) {
            int rowA = wr * 64 + i * 16 + fr;
            offA[kh][i] = (rowA * (BK * 2) + (kg * 8 + kh * 32) * 2) ^ ((rowA & 7) << 4);
            int rowB = wc * 64 + i * 16 + fr;
            offB[kh][i] = (rowB * (BK * 2) + (kg * 8 + kh * 32) * 2) ^ ((rowB & 7) << 4);
        }
    }

    f32x4 aReg[8], bReg[8];
    f32x4 acc[4][4];
    #pragma unroll
    for (int i = 0; i < 4; ++i)
        #pragma unroll
        for (int j = 0; j < 4; ++j)
            acc[i][j] = (f32x4){0.f, 0.f, 0.f, 0.f};

    #pragma unroll
    for (int i = 0; i < 8; ++i) {
        aReg[i] = *(const f32x4*)(pa[i]);
        bReg[i] = *(const f32x4*)(pb[i]);
    }
    #pragma unroll
    for (int i = 0; i < 8; ++i) {
        ushort4 qa, qb;
        qa.x = f2bf(aReg[i].x); qa.y = f2bf(aReg[i].y); qa.z = f2bf(aReg[i].z); qa.w = f2bf(aReg[i].w);
        qb.x = f2bf(bReg[i].x); qb.y = f2bf(bReg[i].y); qb.z = f2bf(bReg[i].z); qb.w = f2bf(bReg[i].w);
        *(ushort4*)((char*)lsA[0] + swz[i]) = qa;
        *(ushort4*)((char*)lsB[0] + swz[i]) = qb;
    }
    __syncthreads();

    for (int kt = 0; kt < KSTEPS; ++kt) {
        int cur = kt & 1;
        int k0n = (kt + 1) * BK;
        if (kt + 1 < KSTEPS) {
            #pragma unroll
            for (int i = 0; i < 8; ++i) {
                aReg[i] = *(const f32x4*)(pa[i] + k0n);
                bReg[i] = *(const f32x4*)(pb[i] + k0n);
            }
        }
        const char* Ab = (const char*)lsA[cur];
        const char* Bb = (const char*)lsB[cur];
        #pragma unroll
        for (int kh = 0; kh < 2; ++kh) {
            bf16x8 af[4], bff[4];
            #pragma unroll
            for (int i = 0; i < 4; ++i) {
                af[i]  = *(const bf16x8*)(Ab + offA[kh][i]);
                bff[i] = *(const bf16x8*)(Bb + offB[kh][i]);
            }
            #pragma unroll
            for (int mi = 0; mi < 4; ++mi)
                #pragma unroll
                for (int ni = 0; ni < 4; ++ni)
                    acc[mi][ni] = __builtin_amdgcn_mfma_f32_16x16x32_bf16(af[mi], bff[ni], acc[mi][ni], 0, 0, 0);
        }
        if (kt + 1 < KSTEPS) {
            int nxt = cur ^ 1;
            #pragma unroll
            for (int i = 0; i < 8; ++i) {
                ushort4 qa, qb;
                qa.x = f2bf(aReg[i].x); qa.y = f2bf(aReg[i].y); qa.z = f2bf(aReg[i].z); qa.w = f2bf(aReg[i].w);
                qb.x = f2bf(bReg[i].x); qb.y = f2bf(bReg[i].y); qb.z = f2bf(bReg[i].z); qb.w = f2bf(bReg[i].w);
                *(ushort4*)((char*)lsA[nxt] + swz[i]) = qa;
                *(ushort4*)((char*)lsB[nxt] + swz[i]) = qb;
            }
        }
        __syncthreads();
    }

    #pragma unroll
    for (int mi = 0; mi < 4; ++mi) {
        #pragma unroll
        for (int j = 0; j < 4; ++j) {
            float mx = acc[mi][0][j];
            mx = fmaxf(mx, acc[mi][1][j]);
            mx = fmaxf(mx, acc[mi][2][j]);
            mx = fmaxf(mx, acc[mi][3][j]);
            #pragma unroll
            for (int s = 1; s < 16; s <<= 1)
                mx = fmaxf(mx, __shfl_xor(mx, s, 64));
            float se = 0.f;
            #pragma unroll
            for (int ni = 0; ni < 4; ++ni)
                se += __expf(acc[mi][ni][j] - mx);
            #pragma unroll
            for (int s = 1; s < 16; s <<= 1)
                se += __shfl_xor(se, s, 64);
            if (fr == 0) {
                int rloc = wr * 64 + mi * 16 + kg * 4 + j;
                red_m[wc][rloc] = mx;
                red_l[wc][rloc] = se;
            }
        }
    }
    __syncthreads();
    if (tid < BM) {
        float m0 = red_m[0][tid], m1 = red_m[1][tid];
        float l0 = red_l[0][tid], l1 = red_l[1][tid];
        float mm = fmaxf(m0, m1);
        float ll = l0 * __expf(m0 - mm) + l1 * __expf(m1 - mm);
        size_t idx = (size_t)vtile * N_ROWS + (size_t)(ntile * BM + tid);
        pm[idx] = mm;
        pl[idx] = ll;
    }
}

// tgt[row] = dot(x[row], W[y[row]]) in fp32 (exact vs reference)
__global__ void lmce_tgt_kernel(const float* __restrict__ X, const float* __restrict__ W,
                                const int* __restrict__ y, float* __restrict__ tgt)
{
    int row = blockIdx.x;
    int tid = threadIdx.x;
    int yv = y[row];
    float s = 0.f;
    if (yv >= 0 && yv < V_DIM) {
        const float* xr = X + (size_t)row * H_DIM;
        const float* wrow = W + (size_t)yv * H_DIM;
        #pragma unroll
        for (int j = 0; j < 4; ++j) {
            int idx = (tid + j * 256) * 4;
            f32x4 a = *(const f32x4*)(xr + idx);
            f32x4 b = *(const f32x4*)(wrow + idx);
            s += a.x * b.x + a.y * b.y + a.z * b.z + a.w * b.w;
        }
    }
    #pragma unroll
    for (int sh = 1; sh < 64; sh <<= 1) s += __shfl_xor(s, sh, 64);
    __shared__ float sred[4];
    if ((tid & 63) == 0) sred[tid >> 6] = s;
    __syncthreads();
    if (tid == 0) tgt[row] = sred[0] + sred[1] + sred[2] + sred[3];
}

// merge 1000 per-vtile (m,l) partials per row -> lse[row]
__global__ void lmce_lse_kernel(const float* __restrict__ pm, const float* __restrict__ pl,
                                float* __restrict__ lse)
{
    int tid = threadIdx.x;
    int row = blockIdx.x * 64 + (tid & 63);
    int part = tid >> 6;
    float m = -INFINITY, l = 0.f;
    for (int vt = part * 250; vt < (part + 1) * 250; ++vt) {
        size_t idx = (size_t)vt * N_ROWS + row;
        float m2 = pm[idx], l2 = pl[idx];
        float mm = fmaxf(m, m2);
        l = l * __expf(m - mm) + l2 * __expf(m2 - mm);
        m = mm;
    }
    __shared__ float sm[4][64], sl[4][64];
    sm[part][tid & 63] = m;
    sl[part][tid & 63] = l;
    __syncthreads();
    if (tid < 64) {
        float M = sm[0][tid], L = sl[0][tid];
        #pragma unroll
        for (int p = 1; p < 4; ++p) {
            float m2 = sm[p][tid], l2 = sl[p][tid];
            float mm = fmaxf(M, m2);
            L = L * __expf(M - mm) + l2 * __expf(m2 - mm);
            M = mm;
        }
        lse[blockIdx.x * 64 + tid] = M + logf(L);
    }
}

__global__ void lmce_final_kernel(const float* __restrict__ lse, const float* __restrict__ tgt,
                                  const int* __restrict__ y, float* __restrict__ out)
{
    int tid = threadIdx.x;
    float s = 0.f, c = 0.f;
    for (int i = tid; i < N_ROWS; i += 256) {
        if (y[i] != IGNORE_INDEX) {
            s += lse[i] - tgt[i];
            c += 1.f;
        }
    }
    #pragma unroll
    for (int sh = 1; sh < 64; sh <<= 1) {
        s += __shfl_xor(s, sh, 64);
        c += __shfl_xor(c, sh, 64);
    }
    __shared__ float ss[4], cc[4];
    if ((tid & 63) == 0) { ss[tid >> 6] = s; cc[tid >> 6] = c; }
    __syncthreads();
    if (tid == 0) {
        float S = ss[0] + ss[1] + ss[2] + ss[3];
        float C = cc[0] + cc[1] + cc[2] + cc[3];
        out[0] = S / fmaxf(C, 1.f);
    }
}

extern "C" void kernel_launch(void* const* d_in, const int* in_sizes, int n_in,
                              void* d_out, int out_size, void* d_ws, size_t ws_size,
                              hipStream_t stream)
{
    const float* X = (const float*)d_in[0];   // [4096, 4096] fp32
    const int*   y = (const int*)d_in[1];     // [4096] labels (int32 from harness)
    const float* W = (const float*)d_in[2];   // [128000, 4096] fp32
    float* out = (float*)d_out;

    char* ws = (char*)d_ws;
    // layout: pm(16,384,000) pl(16,384,000) tgt(16,384) lse(16,384) pad Xb(33,554,432) Wb(1,048,576,000)
    const size_t OFF_PL  = 16384000;
    const size_t OFF_TGT = 32768000;
    const size_t OFF_LSE = 32784384;
    const size_t OFF_XB  = 32800768;
    const size_t OFF_WB  = 66355200;
    const size_t REQ     = OFF_WB + (size_t)V_DIM * H_DIM * 2;  // ~1.04 GB

    float* pm  = (float*)ws;
    float* pl  = (float*)(ws + OFF_PL);
    float* tgt = (float*)(ws + OFF_TGT);
    float* lse = (float*)(ws + OFF_LSE);

    if (ws_size >= REQ) {
        ushort* Xb = (ushort*)(ws + OFF_XB);
        ushort* Wb = (ushort*)(ws + OFF_WB);
        cvt_f32_bf16_kernel<<<2048, 256, 0, stream>>>(W, Wb, (size_t)V_DIM * H_DIM);
        cvt_f32_bf16_kernel<<<512, 256, 0, stream>>>(X, Xb, (size_t)N_ROWS * H_DIM);
        lmce_gemm_bf16_kernel<<<NT_N * NT_V, 256, 0, stream>>>(Xb, Wb, pm, pl);
    } else {
        lmce_gemm_f32_kernel<<<NT_N * NT_V, 256, 0, stream>>>(X, W, pm, pl);
    }
    lmce_tgt_kernel<<<N_ROWS, 256, 0, stream>>>(X, W, y, tgt);
    lmce_lse_kernel<<<N_ROWS / 64, 256, 0, stream>>>(pm, pl, lse);
    lmce_final_kernel<<<1, 256, 0, stream>>>(lse, tgt, y, out);
}

// Round 4
// 5165.706 us; speedup vs baseline: 1.8160x; 1.3341x over previous
//
#include <hip/hip_runtime.h>
#include <hip/hip_bf16.h>
#include <math.h>

// Fused LM-head cross-entropy: loss = mean_valid( logsumexp(x@W^T) - logit[y] )
// N=4096 tokens, H=4096 hidden, V=128000 vocab.
//
// Round 4: 256x256 tile, 8 waves, 4-quadrant phase schedule with counted
// vmcnt (never 0 in the main loop), raw s_barrier, setprio around MFMA
// clusters, deep prefetch: B(t+1) issued at tile-t head, A(t+2) issued after
// the post-ph2 barrier (A region of current buffer is dead by then).

#define N_ROWS 4096
#define H_DIM  4096
#define V_DIM  128000
#define BM 256
#define BN 256
#define BK 64
#define NT_N (N_ROWS / BM)     // 16
#define NT_V (V_DIM / BN)      // 500
#define NK   (H_DIM / BK)      // 64
#define IGNORE_INDEX (-100)

typedef __attribute__((ext_vector_type(8))) short bf16x8;
typedef __attribute__((ext_vector_type(4))) float f32x4;
typedef const __attribute__((address_space(1))) unsigned int* gas1_u32;
typedef __attribute__((address_space(3))) unsigned int* las3_u32;

__device__ __forceinline__ unsigned short f2bf(float f) {
    union { float f; unsigned int u; } v; v.f = f;
    return (unsigned short)((v.u + 0x8000u) >> 16);  // round-half-up to bf16
}

// ---------------- fp32 -> bf16 conversion (memory-bound) ----------------
__global__ void cvt_f32_bf16_kernel(const float* __restrict__ in,
                                    ushort* __restrict__ out, size_t n)
{
    size_t i = ((size_t)blockIdx.x * blockDim.x + threadIdx.x) * 8;
    size_t stride = (size_t)gridDim.x * blockDim.x * 8;
    for (; i < n; i += stride) {
        f32x4 a = *(const f32x4*)(in + i);
        f32x4 b = *(const f32x4*)(in + i + 4);
        ushort4 o0 = { f2bf(a.x), f2bf(a.y), f2bf(a.z), f2bf(a.w) };
        ushort4 o1 = { f2bf(b.x), f2bf(b.y), f2bf(b.z), f2bf(b.w) };
        *(ushort4*)(out + i) = o0;
        *(ushort4*)(out + i + 4) = o1;
    }
}

// ------------------- 256^2 phase-scheduled bf16 GEMM -------------------
__global__ __launch_bounds__(512, 2)
void lmce_gemm256_kernel(const ushort* __restrict__ Xb, const ushort* __restrict__ Wb,
                         float* __restrict__ pm, float* __restrict__ pl)
{
    // [buf][half][128 rows][64 cols] bf16 = 16KB per half; 64KB per operand
    __shared__ __align__(16) ushort lsA[2][2][128 * 64];
    __shared__ __align__(16) ushort lsB[2][2][128 * 64];
    __shared__ float red_m[4][BM];
    __shared__ float red_l[4][BM];

    // bijective XCD swizzle: nwg = 8000, divisible by 8
    const int nwg = NT_N * NT_V;
    int orig = blockIdx.x;
    int wg = (orig & 7) * (nwg >> 3) + (orig >> 3);
    int vtile = wg / NT_N;
    int ntile = wg - vtile * NT_N;

    int tid  = threadIdx.x;
    int lane = tid & 63;
    int w    = tid >> 6;         // 0..7
    int wr = w >> 2;             // 0..1 : row half of output
    int wc = w & 3;              // 0..3 : 64-col strip of output
    int fr = lane & 15;
    int kg = lane >> 4;

    // ---- staging: chunk c = w*2+i covers rows c*8..c*8+7 of a half ----
    // lane l: row_in_chunk = l>>3, LDS col (l&7)*16; source col pre-swizzled
    // with the same XOR the reads use: srccol = ((l&7) ^ (l>>3)) * 16.
    int rin  = lane >> 3;
    int scol = ((lane & 7) ^ rin) * 16;
    const char* gA[2][2];   // [i][h]
    const char* gB[2][2];
    #pragma unroll
    for (int i = 0; i < 2; ++i)
        #pragma unroll
        for (int h = 0; h < 2; ++h) {
            int rowA = ntile * BM + h * 128 + (w * 2 + i) * 8 + rin;
            int rowB = vtile * BN + h * 128 + (w * 2 + i) * 8 + rin;
            gA[i][h] = (const char*)Xb + (size_t)rowA * (H_DIM * 2) + scol;
            gB[i][h] = (const char*)Wb + (size_t)rowB * (H_DIM * 2) + scol;
        }

    auto stageA = [&](int buf, int kt) {
        size_t ko = (size_t)kt * (BK * 2);
        #pragma unroll
        for (int h = 0; h < 2; ++h)
            #pragma unroll
            for (int i = 0; i < 2; ++i)
                __builtin_amdgcn_global_load_lds(
                    (gas1_u32)(gA[i][h] + ko),
                    (las3_u32)((char*)lsA + buf * 32768 + h * 16384 + (w * 2 + i) * 1024),
                    16, 0, 0);
    };
    auto stageB = [&](int buf, int kt) {
        size_t ko = (size_t)kt * (BK * 2);
        #pragma unroll
        for (int h = 0; h < 2; ++h)
            #pragma unroll
            for (int i = 0; i < 2; ++i)
                __builtin_amdgcn_global_load_lds(
                    (gas1_u32)(gB[i][h] + ko),
                    (las3_u32)((char*)lsB + buf * 32768 + h * 16384 + (w * 2 + i) * 1024),
                    16, 0, 0);
    };

    // ---- swizzled ds_read offsets (row&7 == fr&7 since row bases are x16) ----
    int offA[8][2];   // [mi][ks], within lsA + buf*32768
    #pragma unroll
    for (int mi = 0; mi < 8; ++mi)
        #pragma unroll
        for (int ks = 0; ks < 2; ++ks) {
            int row = mi * 16 + fr;
            offA[mi][ks] = wr * 16384 + row * 128 + ((kg * 16 + ks * 64) ^ ((row & 7) << 4));
        }
    int offB[4][2];
    #pragma unroll
    for (int ni = 0; ni < 4; ++ni)
        #pragma unroll
        for (int ks = 0; ks < 2; ++ks) {
            int rowh = (wc & 1) * 64 + ni * 16 + fr;
            offB[ni][ks] = (wc >> 1) * 16384 + rowh * 128 + ((kg * 16 + ks * 64) ^ ((rowh & 7) << 4));
        }

    f32x4 acc[8][4];
    #pragma unroll
    for (int i = 0; i < 8; ++i)
        #pragma unroll
        for (int j = 0; j < 4; ++j)
            acc[i][j] = (f32x4){0.f, 0.f, 0.f, 0.f};

    // prologue: A(0), B(0), A(1)  (12 loads/wave outstanding)
    stageA(0, 0);
    stageB(0, 0);
    stageA(1, 1);

    for (int t = 0; t < NK; ++t) {
        int buf = t & 1;
        const char* Ab = (const char*)lsA + buf * 32768;
        const char* Bb = (const char*)lsB + buf * 32768;

        // tile head: newest 4 outstanding = A(t+2)-class; everything older
        // (A(t), B(t)) must have landed.
        asm volatile("s_waitcnt vmcnt(4)" ::: "memory");
        __builtin_amdgcn_s_barrier();
        asm volatile("" ::: "memory");
        __builtin_amdgcn_sched_barrier(0);

        // issue B(t+1) -> other buffer's B region (dead since tile t-1)
        int tb = (t + 1 < NK) ? (t + 1) : (NK - 1);
        stageB((t + 1) & 1, tb);

        // ph0 ds reads: A[mi 0-3] + all B
        bf16x8 aLo[4][2], bAll[4][2];
        #pragma unroll
        for (int mi = 0; mi < 4; ++mi)
            #pragma unroll
            for (int ks = 0; ks < 2; ++ks)
                aLo[mi][ks] = *(const bf16x8*)(Ab + offA[mi][ks]);
        #pragma unroll
        for (int ni = 0; ni < 4; ++ni)
            #pragma unroll
            for (int ks = 0; ks < 2; ++ks)
                bAll[ni][ks] = *(const bf16x8*)(Bb + offB[ni][ks]);

        // ph0: Q(0,0)
        __builtin_amdgcn_s_setprio(1);
        #pragma unroll
        for (int mi = 0; mi < 4; ++mi)
            #pragma unroll
            for (int ni = 0; ni < 2; ++ni)
                #pragma unroll
                for (int ks = 0; ks < 2; ++ks)
                    acc[mi][ni] = __builtin_amdgcn_mfma_f32_16x16x32_bf16(aLo[mi][ks], bAll[ni][ks], acc[mi][ni], 0, 0, 0);
        __builtin_amdgcn_s_setprio(0);
        __builtin_amdgcn_sched_barrier(0);

        // ph1: Q(0,1)
        __builtin_amdgcn_s_setprio(1);
        #pragma unroll
        for (int mi = 0; mi < 4; ++mi)
            #pragma unroll
            for (int ni = 2; ni < 4; ++ni)
                #pragma unroll
                for (int ks = 0; ks < 2; ++ks)
                    acc[mi][ni] = __builtin_amdgcn_mfma_f32_16x16x32_bf16(aLo[mi][ks], bAll[ni][ks], acc[mi][ni], 0, 0, 0);
        __builtin_amdgcn_s_setprio(0);
        __builtin_amdgcn_sched_barrier(0);

        // ph2: read A[mi 4-7], Q(1,1)
        bf16x8 aHi[4][2];
        #pragma unroll
        for (int mi = 0; mi < 4; ++mi)
            #pragma unroll
            for (int ks = 0; ks < 2; ++ks)
                aHi[mi][ks] = *(const bf16x8*)(Ab + offA[mi + 4][ks]);
        __builtin_amdgcn_s_setprio(1);
        #pragma unroll
        for (int mi = 0; mi < 4; ++mi)
            #pragma unroll
            for (int ni = 2; ni < 4; ++ni)
                #pragma unroll
                for (int ks = 0; ks < 2; ++ks)
                    acc[mi + 4][ni] = __builtin_amdgcn_mfma_f32_16x16x32_bf16(aHi[mi][ks], bAll[ni][ks], acc[mi + 4][ni], 0, 0, 0);
        __builtin_amdgcn_s_setprio(0);
        __builtin_amdgcn_sched_barrier(0);

        // all waves done with this buffer's A region -> safe to overwrite
        __builtin_amdgcn_s_barrier();
        asm volatile("" ::: "memory");
        int ta = (t + 2 < NK) ? (t + 2) : (NK - 1);
        stageA((t + 2) & 1, ta);   // (t+2)&1 == buf : A region of current buffer

        // ph3: Q(1,0)
        __builtin_amdgcn_s_setprio(1);
        #pragma unroll
        for (int mi = 0; mi < 4; ++mi)
            #pragma unroll
            for (int ni = 0; ni < 2; ++ni)
                #pragma unroll
                for (int ks = 0; ks < 2; ++ks)
                    acc[mi + 4][ni] = __builtin_amdgcn_mfma_f32_16x16x32_bf16(aHi[mi][ks], bAll[ni][ks], acc[mi + 4][ni], 0, 0, 0);
        __builtin_amdgcn_s_setprio(0);
        __builtin_amdgcn_sched_barrier(0);
    }

    __syncthreads();   // full drain (incl. dummy tail stages) before epilogue

    // Epilogue: per-row max and sumexp over this block's 256 cols.
    // C/D layout (16x16x32): col = lane&15 (fr), row = kg*4 + reg.
    #pragma unroll
    for (int mi = 0; mi < 8; ++mi) {
        #pragma unroll
        for (int j = 0; j < 4; ++j) {
            float mx = fmaxf(fmaxf(acc[mi][0][j], acc[mi][1][j]),
                             fmaxf(acc[mi][2][j], acc[mi][3][j]));
            #pragma unroll
            for (int s = 1; s < 16; s <<= 1)
                mx = fmaxf(mx, __shfl_xor(mx, s, 64));
            float se = 0.f;
            #pragma unroll
            for (int ni = 0; ni < 4; ++ni)
                se += __expf(acc[mi][ni][j] - mx);
            #pragma unroll
            for (int s = 1; s < 16; s <<= 1)
                se += __shfl_xor(se, s, 64);
            if (fr == 0) {
                int rloc = wr * 128 + mi * 16 + kg * 4 + j;
                red_m[wc][rloc] = mx;
                red_l[wc][rloc] = se;
            }
        }
    }
    __syncthreads();
    if (tid < BM) {
        float mm = red_m[0][tid], ll = red_l[0][tid];
        #pragma unroll
        for (int p = 1; p < 4; ++p) {
            float m2 = red_m[p][tid], l2 = red_l[p][tid];
            float m3 = fmaxf(mm, m2);
            ll = ll * __expf(mm - m3) + l2 * __expf(m2 - m3);
            mm = m3;
        }
        size_t idx = (size_t)vtile * N_ROWS + (size_t)(ntile * BM + tid);
        pm[idx] = mm;
        pl[idx] = ll;
    }
}

// tgt[row] = dot(x[row], W[y[row]]) in fp32 (exact vs reference)
__global__ void lmce_tgt_kernel(const float* __restrict__ X, const float* __restrict__ W,
                                const int* __restrict__ y, float* __restrict__ tgt)
{
    int row = blockIdx.x;
    int tid = threadIdx.x;
    int yv = y[row];
    float s = 0.f;
    if (yv >= 0 && yv < V_DIM) {
        const float* xr = X + (size_t)row * H_DIM;
        const float* wrow = W + (size_t)yv * H_DIM;
        #pragma unroll
        for (int j = 0; j < 4; ++j) {
            int idx = (tid + j * 256) * 4;
            f32x4 a = *(const f32x4*)(xr + idx);
            f32x4 b = *(const f32x4*)(wrow + idx);
            s += a.x * b.x + a.y * b.y + a.z * b.z + a.w * b.w;
        }
    }
    #pragma unroll
    for (int sh = 1; sh < 64; sh <<= 1) s += __shfl_xor(s, sh, 64);
    __shared__ float sred[4];
    if ((tid & 63) == 0) sred[tid >> 6] = s;
    __syncthreads();
    if (tid == 0) tgt[row] = sred[0] + sred[1] + sred[2] + sred[3];
}

// merge NT_V per-vtile (m,l) partials per row -> lse[row]
__global__ void lmce_lse_kernel(const float* __restrict__ pm, const float* __restrict__ pl,
                                float* __restrict__ lse)
{
    int tid = threadIdx.x;
    int row = blockIdx.x * 64 + (tid & 63);
    int part = tid >> 6;               // 0..3, each scans NT_V/4 = 125 vtiles
    const int per = NT_V / 4;
    float m = -INFINITY, l = 0.f;
    for (int vt = part * per; vt < (part + 1) * per; ++vt) {
        size_t idx = (size_t)vt * N_ROWS + row;
        float m2 = pm[idx], l2 = pl[idx];
        float mm = fmaxf(m, m2);
        l = l * __expf(m - mm) + l2 * __expf(m2 - mm);
        m = mm;
    }
    __shared__ float sm[4][64], sl[4][64];
    sm[part][tid & 63] = m;
    sl[part][tid & 63] = l;
    __syncthreads();
    if (tid < 64) {
        float M = sm[0][tid], L = sl[0][tid];
        #pragma unroll
        for (int p = 1; p < 4; ++p) {
            float m2 = sm[p][tid], l2 = sl[p][tid];
            float mm = fmaxf(M, m2);
            L = L * __expf(M - mm) + l2 * __expf(m2 - mm);
            M = mm;
        }
        lse[blockIdx.x * 64 + tid] = M + logf(L);
    }
}

__global__ void lmce_final_kernel(const float* __restrict__ lse, const float* __restrict__ tgt,
                                  const int* __restrict__ y, float* __restrict__ out)
{
    int tid = threadIdx.x;
    float s = 0.f, c = 0.f;
    for (int i = tid; i < N_ROWS; i += 256) {
        if (y[i] != IGNORE_INDEX) {
            s += lse[i] - tgt[i];
            c += 1.f;
        }
    }
    #pragma unroll
    for (int sh = 1; sh < 64; sh <<= 1) {
        s += __shfl_xor(s, sh, 64);
        c += __shfl_xor(c, sh, 64);
    }
    __shared__ float ss[4], cc[4];
    if ((tid & 63) == 0) { ss[tid >> 6] = s; cc[tid >> 6] = c; }
    __syncthreads();
    if (tid == 0) {
        float S = ss[0] + ss[1] + ss[2] + ss[3];
        float C = cc[0] + cc[1] + cc[2] + cc[3];
        out[0] = S / fmaxf(C, 1.f);
    }
}

extern "C" void kernel_launch(void* const* d_in, const int* in_sizes, int n_in,
                              void* d_out, int out_size, void* d_ws, size_t ws_size,
                              hipStream_t stream)
{
    const float* X = (const float*)d_in[0];   // [4096, 4096] fp32
    const int*   y = (const int*)d_in[1];     // [4096] labels
    const float* W = (const float*)d_in[2];   // [128000, 4096] fp32
    float* out = (float*)d_out;

    char* ws = (char*)d_ws;
    // layout (regions sized as round 2/3; pm/pl now use 500x4096 of them):
    const size_t OFF_PL  = 16384000;
    const size_t OFF_TGT = 32768000;
    const size_t OFF_LSE = 32784384;
    const size_t OFF_XB  = 32800768;
    const size_t OFF_WB  = 66355200;

    float* pm  = (float*)ws;
    float* pl  = (float*)(ws + OFF_PL);
    float* tgt = (float*)(ws + OFF_TGT);
    float* lse = (float*)(ws + OFF_LSE);
    ushort* Xb = (ushort*)(ws + OFF_XB);
    ushort* Wb = (ushort*)(ws + OFF_WB);

    cvt_f32_bf16_kernel<<<2048, 256, 0, stream>>>(W, Wb, (size_t)V_DIM * H_DIM);
    cvt_f32_bf16_kernel<<<512, 256, 0, stream>>>(X, Xb, (size_t)N_ROWS * H_DIM);
    lmce_gemm256_kernel<<<NT_N * NT_V, 512, 0, stream>>>(Xb, Wb, pm, pl);
    lmce_tgt_kernel<<<N_ROWS, 256, 0, stream>>>(X, W, y, tgt);
    lmce_lse_kernel<<<N_ROWS / 64, 256, 0, stream>>>(pm, pl, lse);
    lmce_final_kernel<<<1, 256, 0, stream>>>(lse, tgt, y, out);
}

// Round 5
// 4710.978 us; speedup vs baseline: 1.9913x; 1.0965x over previous
//
#include <hip/hip_runtime.h>
#include <hip/hip_bf16.h>
#include <math.h>

// Fused LM-head cross-entropy: loss = mean_valid( logsumexp(x@W^T) - logit[y] )
// N=4096 tokens, H=4096 hidden, V=128000 vocab.
//
// Round 5: m201-style 8-phase schedule. 256x256 tile, BK=64, 8 waves (2Mx4N),
// 128KB LDS (2 dbuf x 2 half x [128][64] x {A,B}). Per phase: ds_read subtile,
// stage ONE half-tile (2 gload_lds/thread), s_barrier, lgkmcnt(0),
// setprio(1) 16xMFMA setprio(0), s_barrier. vmcnt(6) only at end of ph3/ph7.

#define N_ROWS 4096
#define H_DIM  4096
#define V_DIM  128000
#define BM 256
#define BN 256
#define BK 64
#define NT_N (N_ROWS / BM)     // 16
#define NT_V (V_DIM / BN)      // 500
#define NK   (H_DIM / BK)      // 64
#define IGNORE_INDEX (-100)

typedef __attribute__((ext_vector_type(8))) short bf16x8;
typedef __attribute__((ext_vector_type(4))) float f32x4;
typedef const __attribute__((address_space(1))) unsigned int* gas1_u32;
typedef __attribute__((address_space(3))) unsigned int* las3_u32;

__device__ __forceinline__ unsigned short f2bf(float f) {
    union { float f; unsigned int u; } v; v.f = f;
    return (unsigned short)((v.u + 0x8000u) >> 16);  // round-half-up to bf16
}

// ---------------- fp32 -> bf16 conversion (memory-bound) ----------------
__global__ void cvt_f32_bf16_kernel(const float* __restrict__ in,
                                    ushort* __restrict__ out, size_t n)
{
    size_t i = ((size_t)blockIdx.x * blockDim.x + threadIdx.x) * 8;
    size_t stride = (size_t)gridDim.x * blockDim.x * 8;
    for (; i < n; i += stride) {
        f32x4 a = *(const f32x4*)(in + i);
        f32x4 b = *(const f32x4*)(in + i + 4);
        ushort4 o0 = { f2bf(a.x), f2bf(a.y), f2bf(a.z), f2bf(a.w) };
        ushort4 o1 = { f2bf(b.x), f2bf(b.y), f2bf(b.z), f2bf(b.w) };
        *(ushort4*)(out + i) = o0;
        *(ushort4*)(out + i + 4) = o1;
    }
}

#define BAR()    asm volatile("s_barrier" ::: "memory")
#define LGKM0()  asm volatile("s_waitcnt lgkmcnt(0)" ::: "memory")
#define WAITV6() asm volatile("s_waitcnt vmcnt(6)" ::: "memory")
#define SETP1()  __builtin_amdgcn_s_setprio(1)
#define SETP0()  __builtin_amdgcn_s_setprio(0)

// stage one half-tile (2 x 16B gload_lds per thread); dest linear, src pre-swizzled
#define STAGE_A(BUF, HALF, KT)                                                        \
    { _Pragma("unroll")                                                               \
      for (int j_ = 0; j_ < 2; ++j_)                                                  \
          __builtin_amdgcn_global_load_lds(                                           \
              (gas1_u32)(gAr + (size_t)((HALF)*128 + j_*64) * 8192 + (size_t)(KT)*128),\
              (las3_u32)((char*)lsA + (BUF)*32768 + (HALF)*16384 + j_*8192 + tid*16), \
              16, 0, 0); }
#define STAGE_B(BUF, HALF, KT)                                                        \
    { _Pragma("unroll")                                                               \
      for (int j_ = 0; j_ < 2; ++j_)                                                  \
          __builtin_amdgcn_global_load_lds(                                           \
              (gas1_u32)(gBr + (size_t)((HALF)*128 + j_*64) * 8192 + (size_t)(KT)*128),\
              (las3_u32)((char*)lsB + (BUF)*32768 + (HALF)*16384 + j_*8192 + tid*16), \
              16, 0, 0); }

#define RD_ALO(BUF)                                                                   \
    { _Pragma("unroll")                                                               \
      for (int mi_ = 0; mi_ < 4; ++mi_) { _Pragma("unroll")                           \
        for (int ks_ = 0; ks_ < 2; ++ks_)                                             \
          aLo[mi_][ks_] = *(const bf16x8*)((const char*)lsA + (BUF)*32768 + offA[mi_][ks_]); } }
#define RD_AHI(BUF)                                                                   \
    { _Pragma("unroll")                                                               \
      for (int mi_ = 0; mi_ < 4; ++mi_) { _Pragma("unroll")                           \
        for (int ks_ = 0; ks_ < 2; ++ks_)                                             \
          aHi[mi_][ks_] = *(const bf16x8*)((const char*)lsA + (BUF)*32768 + offA[mi_ + 4][ks_]); } }
#define RD_BLO(BUF)                                                                   \
    { _Pragma("unroll")                                                               \
      for (int ni_ = 0; ni_ < 2; ++ni_) { _Pragma("unroll")                           \
        for (int ks_ = 0; ks_ < 2; ++ks_)                                             \
          bAll[ni_][ks_] = *(const bf16x8*)((const char*)lsB + (BUF)*32768 + offB[ni_][ks_]); } }
#define RD_BHI(BUF)                                                                   \
    { _Pragma("unroll")                                                               \
      for (int ni_ = 2; ni_ < 4; ++ni_) { _Pragma("unroll")                           \
        for (int ks_ = 0; ks_ < 2; ++ks_)                                             \
          bAll[ni_][ks_] = *(const bf16x8*)((const char*)lsB + (BUF)*32768 + offB[ni_][ks_]); } }

#define MFMA_QUAD(AF, MIB, NIL)                                                       \
    { _Pragma("unroll")                                                               \
      for (int mi_ = 0; mi_ < 4; ++mi_) { _Pragma("unroll")                           \
        for (int nn_ = 0; nn_ < 2; ++nn_) { _Pragma("unroll")                         \
          for (int ks_ = 0; ks_ < 2; ++ks_)                                           \
            acc[(MIB)+mi_][(NIL)+nn_] = __builtin_amdgcn_mfma_f32_16x16x32_bf16(      \
                AF[mi_][ks_], bAll[(NIL)+nn_][ks_], acc[(MIB)+mi_][(NIL)+nn_], 0, 0, 0); } } }

// ------------------- 256^2 8-phase bf16 GEMM -------------------
__global__ __launch_bounds__(512, 2)
void lmce_gemm256_kernel(const ushort* __restrict__ Xb, const ushort* __restrict__ Wb,
                         float* __restrict__ pm, float* __restrict__ pl)
{
    // [buf][half][128 rows][64 k] bf16 = 16KB per half; 64KB per operand
    __shared__ __align__(16) ushort lsA[2][2][128 * 64];
    __shared__ __align__(16) ushort lsB[2][2][128 * 64];
    __shared__ float red_m[4][BM];
    __shared__ float red_l[4][BM];

    // bijective XCD swizzle: nwg = 8000, divisible by 8
    const int nwg = NT_N * NT_V;
    int orig = blockIdx.x;
    int wg = (orig & 7) * (nwg >> 3) + (orig >> 3);
    int vtile = wg / NT_N;
    int ntile = wg - vtile * NT_N;

    int tid  = threadIdx.x;
    int lane = tid & 63;
    int w    = tid >> 6;         // 0..7
    int wr = w >> 2;             // 0..1 : which A half this wave consumes
    int wc = w & 3;              // 0..3 : which 64-row B strip
    int fr = lane & 15;
    int kg = lane >> 4;

    // staging source: thread covers row (tid>>3) of each 64-row chunk,
    // 16B at pre-swizzled col ((tid&7) ^ ((tid>>3)&7))*16
    int scolb = ((tid & 7) ^ ((tid >> 3) & 7)) * 16;
    const char* gAr = (const char*)Xb + (size_t)(ntile * BM + (tid >> 3)) * 8192 + scolb;
    const char* gBr = (const char*)Wb + (size_t)(vtile * BN + (tid >> 3)) * 8192 + scolb;

    // swizzled ds_read offsets (within one operand buffer; add buf*32768)
    int offA[8][2];
    #pragma unroll
    for (int mi = 0; mi < 8; ++mi)
        #pragma unroll
        for (int ks = 0; ks < 2; ++ks) {
            int row = mi * 16 + fr;     // local row in half wr
            offA[mi][ks] = wr * 16384 + row * 128 + ((kg * 16 + ks * 64) ^ ((row & 7) << 4));
        }
    int offB[4][2];
    #pragma unroll
    for (int ni = 0; ni < 4; ++ni)
        #pragma unroll
        for (int ks = 0; ks < 2; ++ks) {
            int rowh = (wc & 1) * 64 + ni * 16 + fr;   // local row in half wc>>1
            offB[ni][ks] = (wc >> 1) * 16384 + rowh * 128 + ((kg * 16 + ks * 64) ^ ((rowh & 7) << 4));
        }

    f32x4 acc[8][4];
    #pragma unroll
    for (int i = 0; i < 8; ++i)
        #pragma unroll
        for (int j = 0; j < 4; ++j)
            acc[i][j] = (f32x4){0.f, 0.f, 0.f, 0.f};

    bf16x8 aLo[4][2], aHi[4][2], bAll[4][2];

    // prologue: tile0 (8 loads) + {B0(1),B1(1),A0(1)} (6 loads in flight)
    STAGE_A(0, 0, 0); STAGE_A(0, 1, 0); STAGE_B(0, 0, 0); STAGE_B(0, 1, 0);
    STAGE_B(1, 0, 1); STAGE_B(1, 1, 1); STAGE_A(1, 0, 1);
    WAITV6();
    BAR();

    for (int t = 0; t < NK; t += 2) {
        int t2 = (t + 2 < NK) ? t + 2 : NK - 1;   // clamped dummy re-stage at tail
        int t3 = (t + 3 < NK) ? t + 3 : NK - 1;

        // ---- ph0 (tile t, buf0): Q(mi0-3, ni0-1)
        RD_ALO(0); RD_BLO(0);
        STAGE_A(1, 1, t + 1);
        BAR(); LGKM0();
        SETP1(); MFMA_QUAD(aLo, 0, 0); SETP0();
        BAR();

        // ---- ph1: Q(mi0-3, ni2-3)
        RD_BHI(0);
        STAGE_B(0, 0, t2);
        BAR(); LGKM0();
        SETP1(); MFMA_QUAD(aLo, 0, 2); SETP0();
        BAR();

        // ---- ph2: Q(mi4-7, ni2-3)
        RD_AHI(0);
        STAGE_B(0, 1, t2);
        BAR(); LGKM0();
        SETP1(); MFMA_QUAD(aHi, 4, 2); SETP0();
        BAR();

        // ---- ph3: Q(mi4-7, ni0-1); tile t+1 must land before ph4 reads
        STAGE_A(0, 0, t2);
        BAR(); LGKM0();
        SETP1(); MFMA_QUAD(aHi, 4, 0); SETP0();
        WAITV6();
        BAR();

        // ---- ph4 (tile t+1, buf1): Q(mi0-3, ni0-1)
        RD_ALO(1); RD_BLO(1);
        STAGE_A(0, 1, t2);
        BAR(); LGKM0();
        SETP1(); MFMA_QUAD(aLo, 0, 0); SETP0();
        BAR();

        // ---- ph5: Q(mi0-3, ni2-3)
        RD_BHI(1);
        STAGE_B(1, 0, t3);
        BAR(); LGKM0();
        SETP1(); MFMA_QUAD(aLo, 0, 2); SETP0();
        BAR();

        // ---- ph6: Q(mi4-7, ni2-3)
        RD_AHI(1);
        STAGE_B(1, 1, t3);
        BAR(); LGKM0();
        SETP1(); MFMA_QUAD(aHi, 4, 2); SETP0();
        BAR();

        // ---- ph7: Q(mi4-7, ni0-1); tile t+2 must land before next ph0 reads
        STAGE_A(1, 0, t3);
        BAR(); LGKM0();
        SETP1(); MFMA_QUAD(aHi, 4, 0); SETP0();
        WAITV6();
        BAR();
    }

    __syncthreads();   // full drain (vmcnt 0 + lgkm 0) before epilogue

    // Epilogue: per-row max and sumexp over this block's 256 cols.
    // C/D layout (16x16x32): col = lane&15 (fr), row = kg*4 + reg.
    #pragma unroll
    for (int mi = 0; mi < 8; ++mi) {
        #pragma unroll
        for (int j = 0; j < 4; ++j) {
            float mx = fmaxf(fmaxf(acc[mi][0][j], acc[mi][1][j]),
                             fmaxf(acc[mi][2][j], acc[mi][3][j]));
            #pragma unroll
            for (int s = 1; s < 16; s <<= 1)
                mx = fmaxf(mx, __shfl_xor(mx, s, 64));
            float se = 0.f;
            #pragma unroll
            for (int ni = 0; ni < 4; ++ni)
                se += __expf(acc[mi][ni][j] - mx);
            #pragma unroll
            for (int s = 1; s < 16; s <<= 1)
                se += __shfl_xor(se, s, 64);
            if (fr == 0) {
                int rloc = wr * 128 + mi * 16 + kg * 4 + j;
                red_m[wc][rloc] = mx;
                red_l[wc][rloc] = se;
            }
        }
    }
    __syncthreads();
    if (tid < BM) {
        float mm = red_m[0][tid], ll = red_l[0][tid];
        #pragma unroll
        for (int p = 1; p < 4; ++p) {
            float m2 = red_m[p][tid], l2 = red_l[p][tid];
            float m3 = fmaxf(mm, m2);
            ll = ll * __expf(mm - m3) + l2 * __expf(m2 - m3);
            mm = m3;
        }
        size_t idx = (size_t)vtile * N_ROWS + (size_t)(ntile * BM + tid);
        pm[idx] = mm;
        pl[idx] = ll;
    }
}

// tgt[row] = dot(x[row], W[y[row]]) in fp32 (exact vs reference)
__global__ void lmce_tgt_kernel(const float* __restrict__ X, const float* __restrict__ W,
                                const int* __restrict__ y, float* __restrict__ tgt)
{
    int row = blockIdx.x;
    int tid = threadIdx.x;
    int yv = y[row];
    float s = 0.f;
    if (yv >= 0 && yv < V_DIM) {
        const float* xr = X + (size_t)row * H_DIM;
        const float* wrow = W + (size_t)yv * H_DIM;
        #pragma unroll
        for (int j = 0; j < 4; ++j) {
            int idx = (tid + j * 256) * 4;
            f32x4 a = *(const f32x4*)(xr + idx);
            f32x4 b = *(const f32x4*)(wrow + idx);
            s += a.x * b.x + a.y * b.y + a.z * b.z + a.w * b.w;
        }
    }
    #pragma unroll
    for (int sh = 1; sh < 64; sh <<= 1) s += __shfl_xor(s, sh, 64);
    __shared__ float sred[4];
    if ((tid & 63) == 0) sred[tid >> 6] = s;
    __syncthreads();
    if (tid == 0) tgt[row] = sred[0] + sred[1] + sred[2] + sred[3];
}

// merge NT_V per-vtile (m,l) partials per row -> lse[row]
__global__ void lmce_lse_kernel(const float* __restrict__ pm, const float* __restrict__ pl,
                                float* __restrict__ lse)
{
    int tid = threadIdx.x;
    int row = blockIdx.x * 64 + (tid & 63);
    int part = tid >> 6;               // 0..3, each scans NT_V/4 = 125 vtiles
    const int per = NT_V / 4;
    float m = -INFINITY, l = 0.f;
    for (int vt = part * per; vt < (part + 1) * per; ++vt) {
        size_t idx = (size_t)vt * N_ROWS + row;
        float m2 = pm[idx], l2 = pl[idx];
        float mm = fmaxf(m, m2);
        l = l * __expf(m - mm) + l2 * __expf(m2 - mm);
        m = mm;
    }
    __shared__ float sm[4][64], sl[4][64];
    sm[part][tid & 63] = m;
    sl[part][tid & 63] = l;
    __syncthreads();
    if (tid < 64) {
        float M = sm[0][tid], L = sl[0][tid];
        #pragma unroll
        for (int p = 1; p < 4; ++p) {
            float m2 = sm[p][tid], l2 = sl[p][tid];
            float mm = fmaxf(M, m2);
            L = L * __expf(M - mm) + l2 * __expf(m2 - mm);
            M = mm;
        }
        lse[blockIdx.x * 64 + tid] = M + logf(L);
    }
}

__global__ void lmce_final_kernel(const float* __restrict__ lse, const float* __restrict__ tgt,
                                  const int* __restrict__ y, float* __restrict__ out)
{
    int tid = threadIdx.x;
    float s = 0.f, c = 0.f;
    for (int i = tid; i < N_ROWS; i += 256) {
        if (y[i] != IGNORE_INDEX) {
            s += lse[i] - tgt[i];
            c += 1.f;
        }
    }
    #pragma unroll
    for (int sh = 1; sh < 64; sh <<= 1) {
        s += __shfl_xor(s, sh, 64);
        c += __shfl_xor(c, sh, 64);
    }
    __shared__ float ss[4], cc[4];
    if ((tid & 63) == 0) { ss[tid >> 6] = s; cc[tid >> 6] = c; }
    __syncthreads();
    if (tid == 0) {
        float S = ss[0] + ss[1] + ss[2] + ss[3];
        float C = cc[0] + cc[1] + cc[2] + cc[3];
        out[0] = S / fmaxf(C, 1.f);
    }
}

extern "C" void kernel_launch(void* const* d_in, const int* in_sizes, int n_in,
                              void* d_out, int out_size, void* d_ws, size_t ws_size,
                              hipStream_t stream)
{
    const float* X = (const float*)d_in[0];   // [4096, 4096] fp32
    const int*   y = (const int*)d_in[1];     // [4096] labels
    const float* W = (const float*)d_in[2];   // [128000, 4096] fp32
    float* out = (float*)d_out;

    char* ws = (char*)d_ws;
    const size_t OFF_PL  = 16384000;
    const size_t OFF_TGT = 32768000;
    const size_t OFF_LSE = 32784384;
    const size_t OFF_XB  = 32800768;
    const size_t OFF_WB  = 66355200;

    float* pm  = (float*)ws;
    float* pl  = (float*)(ws + OFF_PL);
    float* tgt = (float*)(ws + OFF_TGT);
    float* lse = (float*)(ws + OFF_LSE);
    ushort* Xb = (ushort*)(ws + OFF_XB);
    ushort* Wb = (ushort*)(ws + OFF_WB);

    cvt_f32_bf16_kernel<<<2048, 256, 0, stream>>>(W, Wb, (size_t)V_DIM * H_DIM);
    cvt_f32_bf16_kernel<<<512, 256, 0, stream>>>(X, Xb, (size_t)N_ROWS * H_DIM);
    lmce_gemm256_kernel<<<NT_N * NT_V, 512, 0, stream>>>(Xb, Wb, pm, pl);
    lmce_tgt_kernel<<<N_ROWS, 256, 0, stream>>>(X, W, y, tgt);
    lmce_lse_kernel<<<N_ROWS / 64, 256, 0, stream>>>(pm, pl, lse);
    lmce_final_kernel<<<1, 256, 0, stream>>>(lse, tgt, y, out);
}